// Round 1
// baseline (1444.738 us; speedup 1.0000x reference)
//
#include <hip/hip_runtime.h>

#define NROWS 16384
#define KCODES 8192
#define DDIM 256
#define OUT_LOSS 4194304
#define OUT_CODES 4194305

// ---------------- main: fused distance + argmin ----------------
// grid 256 blocks (64 rows each), 512 threads: thread tile 4 rows x 4 cols,
// block tile 64 rows x 128 codes per k-chunk, D staged in 32-wide LDS chunks.
__global__ __launch_bounds__(512, 2) void vq_main(const float* __restrict__ z_e,
                                                  const float* __restrict__ emb,
                                                  float* __restrict__ out)
{
    __shared__ float As[32][68];    // [d][row], padded for 16B-aligned rows
    __shared__ float Bs[32][132];   // [d][k]
    __shared__ float x2s[64];
    __shared__ unsigned long long best[64];

    const int tid  = threadIdx.x;
    const int row0 = blockIdx.x * 64;
    const int tx   = tid & 31;   // 0..31 -> k-quad
    const int ty   = tid >> 5;   // 0..15 -> row-quad

    // zero the loss accumulator slot (epilogue kernel atomicAdds into it)
    if (blockIdx.x == 0 && tid == 0) out[OUT_LOSS] = 0.0f;

    // x2 prologue: numpy pairwise order (2 halves of 128, 8 accumulators each).
    // All ops via _rn intrinsics so -ffp-contract can't fuse mul+add.
    if (tid < 64) {
        const float* rp = z_e + (size_t)(row0 + tid) * DDIM;
        float hr[2];
        #pragma unroll
        for (int h = 0; h < 2; ++h) {
            const float* a = rp + h * 128;
            float r[8];
            #pragma unroll
            for (int j = 0; j < 8; ++j) { const float v = a[j]; r[j] = __fmul_rn(v, v); }
            #pragma unroll 1
            for (int i = 8; i < 128; i += 8) {
                #pragma unroll
                for (int j = 0; j < 8; ++j) {
                    const float v = a[i + j];
                    r[j] = __fadd_rn(r[j], __fmul_rn(v, v));
                }
            }
            hr[h] = __fadd_rn(__fadd_rn(__fadd_rn(r[0], r[1]), __fadd_rn(r[2], r[3])),
                              __fadd_rn(__fadd_rn(r[4], r[5]), __fadd_rn(r[6], r[7])));
        }
        x2s[tid] = __fadd_rn(hr[0], hr[1]);
        best[tid] = ~0ull;
    }
    __syncthreads();

    float x2r[4];
    #pragma unroll
    for (int i = 0; i < 4; ++i) x2r[i] = x2s[ty * 4 + i];

    unsigned long long lb[4] = { ~0ull, ~0ull, ~0ull, ~0ull };

    // staging index maps
    const int a_row = tid >> 3, a_sub = tid & 7;  // 64 rows x (8 x float4 over d)
    const int b_k   = tid >> 2, b_sub = tid & 3;  // 128 k x (4 x 8-float over d)
    const float* a_gp  = z_e + (size_t)(row0 + a_row) * DDIM + a_sub * 4;
    const float* b_gp0 = emb + (size_t)b_k * DDIM + b_sub * 8;

    for (int kc = 0; kc < KCODES; kc += 128) {
        float acc[4][4];
        #pragma unroll
        for (int i = 0; i < 4; ++i)
            #pragma unroll
            for (int j = 0; j < 4; ++j) acc[i][j] = 0.0f;

        const float* b_gp = b_gp0 + (size_t)kc * DDIM;

        for (int dc = 0; dc < DDIM; dc += 32) {
            __syncthreads();
            // stage A chunk (transposed): 64 rows x 32 d
            {
                const float4 v = *(const float4*)(a_gp + dc);
                As[a_sub * 4 + 0][a_row] = v.x;
                As[a_sub * 4 + 1][a_row] = v.y;
                As[a_sub * 4 + 2][a_row] = v.z;
                As[a_sub * 4 + 3][a_row] = v.w;
            }
            // stage B chunk (transposed): 128 k x 32 d
            {
                const float4 w0 = *(const float4*)(b_gp + dc);
                const float4 w1 = *(const float4*)(b_gp + dc + 4);
                Bs[b_sub * 8 + 0][b_k] = w0.x;
                Bs[b_sub * 8 + 1][b_k] = w0.y;
                Bs[b_sub * 8 + 2][b_k] = w0.z;
                Bs[b_sub * 8 + 3][b_k] = w0.w;
                Bs[b_sub * 8 + 4][b_k] = w1.x;
                Bs[b_sub * 8 + 5][b_k] = w1.y;
                Bs[b_sub * 8 + 6][b_k] = w1.z;
                Bs[b_sub * 8 + 7][b_k] = w1.w;
            }
            __syncthreads();

            const float* ap = &As[0][ty * 4];
            const float* bp = &Bs[0][tx * 4];
            #pragma unroll 8
            for (int d = 0; d < 32; ++d) {
                const float4 a4 = *(const float4*)(ap + d * 68);
                const float4 b4 = *(const float4*)(bp + d * 132);
                const float av[4] = { a4.x, a4.y, a4.z, a4.w };
                const float bv[4] = { b4.x, b4.y, b4.z, b4.w };
                #pragma unroll
                for (int i = 0; i < 4; ++i)
                    #pragma unroll
                    for (int j = 0; j < 4; ++j)
                        acc[i][j] = __fmaf_rn(av[i], bv[j], acc[i][j]);
            }
        }

        // dist = fl(x2 - fl(2*dot)); pack (dist_bits, k) so u64-min gives the
        // reference's first-index tie-break. dist > 0 always (x2 ~ 150..370).
        #pragma unroll
        for (int i = 0; i < 4; ++i) {
            #pragma unroll
            for (int j = 0; j < 4; ++j) {
                const float dist = __fsub_rn(x2r[i], __fmul_rn(2.0f, acc[i][j]));
                const unsigned long long key =
                    ((unsigned long long)__float_as_uint(dist) << 32) |
                    (unsigned)(kc + tx * 4 + j);
                lb[i] = (key < lb[i]) ? key : lb[i];
            }
        }
    }

    #pragma unroll
    for (int i = 0; i < 4; ++i) atomicMin(&best[ty * 4 + i], lb[i]);
    __syncthreads();

    if (tid < 64) {
        const unsigned code = (unsigned)(best[tid] & 0xFFFFFFFFull);
        out[OUT_CODES + row0 + tid] = (float)code;   // codes emitted as f32
    }
}

// ---------------- epilogue: gather z_q, z_q_st, loss ----------------
__global__ __launch_bounds__(256) void vq_epilogue(const float* __restrict__ z_e,
                                                   const float* __restrict__ emb,
                                                   float* __restrict__ out)
{
    const int row = blockIdx.x;
    const int d   = threadIdx.x;
    const int code = (int)out[OUT_CODES + row];

    const float zq = emb[(size_t)code * DDIM + d];
    const float ze = z_e[(size_t)row * DDIM + d];
    const float diff = __fsub_rn(zq, ze);
    out[(size_t)row * DDIM + d] = __fadd_rn(ze, diff);  // z_q_st = z_e + (z_q - z_e)

    float p = __fmul_rn(diff, diff);
    #pragma unroll
    for (int o = 32; o > 0; o >>= 1) p += __shfl_down(p, o);

    __shared__ float ws[4];
    if ((d & 63) == 0) ws[d >> 6] = p;
    __syncthreads();
    if (d == 0) {
        const float s = ((ws[0] + ws[1]) + (ws[2] + ws[3]));
        // loss = emb_loss + 0.25*commit_loss = 1.25 * mean(diff^2)
        atomicAdd(&out[OUT_LOSS], s * (1.25f / 4194304.0f));
    }
}

extern "C" void kernel_launch(void* const* d_in, const int* in_sizes, int n_in,
                              void* d_out, int out_size, void* d_ws, size_t ws_size,
                              hipStream_t stream) {
    const float* z_e = (const float*)d_in[0];
    const float* emb = (const float*)d_in[1];
    float* out = (float*)d_out;
    (void)in_sizes; (void)n_in; (void)out_size; (void)d_ws; (void)ws_size;

    vq_main<<<dim3(NROWS / 64), dim3(512), 0, stream>>>(z_e, emb, out);
    vq_epilogue<<<dim3(NROWS), dim3(256), 0, stream>>>(z_e, emb, out);
}